// Round 1
// baseline (469.660 us; speedup 1.0000x reference)
//
#include <hip/hip_runtime.h>
#include <hip/hip_bf16.h>

#define N_NODES 20000
#define N_EDGES 32768
#define DIM 128
#define N_REL 474
#define N_BASIS 64

// ---------- helpers ----------
__device__ __forceinline__ unsigned ordf(float f) {
    unsigned u = __float_as_uint(f);
    return (u & 0x80000000u) ? ~u : (u | 0x80000000u);
}
__device__ __forceinline__ float unordf(unsigned u) {
    unsigned v = (u & 0x80000000u) ? (u & 0x7FFFFFFFu) : ~u;
    return __uint_as_float(v);
}

// ---------- x0 = emb[entity] ----------
__global__ void gather_kernel(const float4* __restrict__ emb, const int* __restrict__ entity,
                              float4* __restrict__ x0, int total4) {
    int i = blockIdx.x * blockDim.x + threadIdx.x;
    if (i >= total4) return;
    int n = i >> 5;       // 32 float4 per node
    int rem = i & 31;
    x0[i] = emb[(size_t)entity[n] * 32 + rem];
}

// ---------- edge grouping by relation ----------
__global__ void count_kernel(const int* __restrict__ et, int* __restrict__ cnt, int E) {
    int e = blockIdx.x * blockDim.x + threadIdx.x;
    if (e < E) atomicAdd(&cnt[et[e]], 1);
}

__global__ void scan_kernel(const int* __restrict__ cnt, int* __restrict__ offs,
                            int* __restrict__ cursor, int R, int E) {
    __shared__ int s[512];
    int t = threadIdx.x;
    int v = (t < R) ? cnt[t] : 0;
    s[t] = v;
    __syncthreads();
    for (int d = 1; d < 512; d <<= 1) {
        int add = (t >= d) ? s[t - d] : 0;
        __syncthreads();
        s[t] += add;
        __syncthreads();
    }
    if (t < R) { int excl = s[t] - v; offs[t] = excl; cursor[t] = excl; }
    if (t == 0) offs[R] = E;
}

__global__ void scatter_kernel(const int* __restrict__ et, int* __restrict__ cursor,
                               int* __restrict__ eids, int E) {
    int e = blockIdx.x * blockDim.x + threadIdx.x;
    if (e < E) {
        int p = atomicAdd(&cursor[et[e]], 1);
        eids[p] = e;
    }
}

// ---------- per-edge attention logit + segment max ----------
__global__ __launch_bounds__(256) void logit_kernel(const float* __restrict__ x,
                                                    const float* __restrict__ w,
                                                    const int* __restrict__ src,
                                                    const int* __restrict__ dst,
                                                    const int* __restrict__ et,
                                                    float* __restrict__ alpha,
                                                    unsigned* __restrict__ nmax, int E) {
    int wid = (blockIdx.x * 256 + threadIdx.x) >> 6;
    int lane = threadIdx.x & 63;
    if (wid >= E) return;
    int s = src[wid], d = dst[wid], r = et[wid];
    const float* xs_ = x + (size_t)s * DIM;
    const float* xd_ = x + (size_t)d * DIM;
    const float* wr_ = w + (size_t)r * DIM;
    float v = xs_[lane] * wr_[lane] * xd_[lane]
            + xs_[lane + 64] * wr_[lane + 64] * xd_[lane + 64];
    for (int off = 32; off > 0; off >>= 1) v += __shfl_xor(v, off, 64);
    if (lane == 0) {
        alpha[wid] = v;
        atomicMax(&nmax[d], ordf(v));
    }
}

// ---------- exp(alpha - max) + segment denom ----------
__global__ void expden_kernel(float* __restrict__ alpha, const int* __restrict__ dst,
                              const unsigned* __restrict__ nmax, float* __restrict__ denom, int E) {
    int e = blockIdx.x * blockDim.x + threadIdx.x;
    if (e >= E) return;
    int d = dst[e];
    float m = unordf(nmax[d]);
    float a = expf(alpha[e] - m);
    alpha[e] = a;
    atomicAdd(&denom[d], a);
}

// ---------- W[r] = sum_b att[r,b] * basis[b]  (att [R,B] @ basis [B, D*D]) ----------
__global__ __launch_bounds__(256) void wmix_kernel(const float* __restrict__ att,
                                                   const float* __restrict__ basis,
                                                   float* __restrict__ W, int R) {
    int io0 = blockIdx.x * 256;     // 64 chunks of 256 over D*D=16384
    int r0 = blockIdx.y * 16;       // 30 tiles of 16 over R
    int t = threadIdx.x;
    __shared__ float atts[16 * 64];
    for (int k = t; k < 16 * 64; k += 256) {
        int rr = k >> 6, b = k & 63;
        atts[k] = (r0 + rr < R) ? att[(size_t)(r0 + rr) * N_BASIS + b] : 0.0f;
    }
    __syncthreads();
    float acc[16];
#pragma unroll
    for (int k = 0; k < 16; k++) acc[k] = 0.0f;
    const float* bp = basis + io0 + t;
    for (int b = 0; b < N_BASIS; b++) {
        float bv = bp[(size_t)b * (DIM * DIM)];
#pragma unroll
        for (int rr = 0; rr < 16; rr++) acc[rr] = fmaf(atts[rr * 64 + b], bv, acc[rr]);
    }
#pragma unroll
    for (int rr = 0; rr < 16; rr++) {
        if (r0 + rr < R) W[(size_t)(r0 + rr) * (DIM * DIM) + io0 + t] = acc[rr];
    }
}

// ---------- per-edge transform + softmax scale + scatter-add ----------
__global__ __launch_bounds__(128) void msg_kernel(const float* __restrict__ x,
                                                  const float* __restrict__ W,
                                                  const int* __restrict__ eids,
                                                  const int* __restrict__ offs,
                                                  const int* __restrict__ src,
                                                  const int* __restrict__ dst,
                                                  const float* __restrict__ ae,
                                                  const float* __restrict__ denom,
                                                  float* __restrict__ out) {
    int r = blockIdx.x;
    int start = offs[r], end = offs[r + 1];
    if (start >= end) return;
    const float* Wr = W + (size_t)r * (DIM * DIM);
    int o = threadIdx.x;  // 0..127
    __shared__ float xj[4][DIM];
    __shared__ float cf[4];
    __shared__ int dd[4], ss[4];
    for (int base = start + blockIdx.y * 4; base < end; base += 8) {
        int nE = min(4, end - base);
        if (o < 4 && o < nE) {
            int e = eids[base + o];
            int d_ = dst[e];
            ss[o] = src[e];
            dd[o] = d_;
            cf[o] = ae[e] / denom[d_];
        }
        __syncthreads();
#pragma unroll
        for (int k = 0; k < 4; k++)
            if (k < nE) xj[k][o] = x[(size_t)ss[k] * DIM + o];
        __syncthreads();
        float a0 = 0.f, a1 = 0.f, a2 = 0.f, a3 = 0.f;
#pragma unroll 8
        for (int i = 0; i < DIM; i++) {
            float wv = Wr[i * DIM + o];
            a0 = fmaf(xj[0][i], wv, a0);
            a1 = fmaf(xj[1][i], wv, a1);
            a2 = fmaf(xj[2][i], wv, a2);
            a3 = fmaf(xj[3][i], wv, a3);
        }
        float av0 = a0, av1 = a1, av2 = a2, av3 = a3;
        if (0 < nE) atomicAdd(&out[(size_t)dd[0] * DIM + o], cf[0] * av0);
        if (1 < nE) atomicAdd(&out[(size_t)dd[1] * DIM + o], cf[1] * av1);
        if (2 < nE) atomicAdd(&out[(size_t)dd[2] * DIM + o], cf[2] * av2);
        if (3 < nE) atomicAdd(&out[(size_t)dd[3] * DIM + o], cf[3] * av3);
        __syncthreads();
    }
}

// ---------- out = acc + x @ root + bias (optional relu) ----------
__global__ __launch_bounds__(128) void root_kernel(const float* __restrict__ x,
                                                   const float* __restrict__ rootM,
                                                   const float* __restrict__ bias,
                                                   const float* __restrict__ acc,
                                                   float* __restrict__ out, int relu, int N) {
    int n0 = blockIdx.x * 8;
    int o = threadIdx.x;
    __shared__ float xs[8][DIM];
#pragma unroll
    for (int k = 0; k < 8; k++) {
        int n = n0 + k;
        if (n < N) xs[k][o] = x[(size_t)n * DIM + o];
    }
    __syncthreads();
    float a[8] = {0, 0, 0, 0, 0, 0, 0, 0};
    for (int i = 0; i < DIM; i++) {
        float rv = rootM[i * DIM + o];
#pragma unroll
        for (int k = 0; k < 8; k++) a[k] = fmaf(xs[k][i], rv, a[k]);
    }
    float bo = bias[o];
#pragma unroll
    for (int k = 0; k < 8; k++) {
        int n = n0 + k;
        if (n < N) {
            float v = acc[(size_t)n * DIM + o] + a[k] + bo;
            if (relu) v = fmaxf(v, 0.f);
            out[(size_t)n * DIM + o] = v;
        }
    }
}

extern "C" void kernel_launch(void* const* d_in, const int* in_sizes, int n_in,
                              void* d_out, int out_size, void* d_ws, size_t ws_size,
                              hipStream_t stream) {
    const int N = N_NODES, E = N_EDGES, D = DIM, R = N_REL;

    const int* entity = (const int*)d_in[0];
    const int* eidx   = (const int*)d_in[1];
    const int* src    = eidx;
    const int* dst    = eidx + E;
    const int* etype  = (const int*)d_in[2];
    const float* emb  = (const float*)d_in[3];
    const float* basis1 = (const float*)d_in[4];
    const float* att1   = (const float*)d_in[5];
    const float* w1     = (const float*)d_in[6];
    const float* root1  = (const float*)d_in[7];
    const float* bias1  = (const float*)d_in[8];
    const float* basis2 = (const float*)d_in[9];
    const float* att2   = (const float*)d_in[10];
    const float* w2     = (const float*)d_in[11];
    const float* root2  = (const float*)d_in[12];
    const float* bias2  = (const float*)d_in[13];
    float* out = (float*)d_out;

    // workspace layout (256B aligned chunks)
    size_t off = 0;
    auto alloc = [&](size_t bytes) -> void* {
        void* p = (char*)d_ws + off;
        off += (bytes + 255) & ~(size_t)255;
        return p;
    };
    float* W      = (float*)alloc((size_t)R * D * D * 4);
    float* x0     = (float*)alloc((size_t)N * D * 4);
    float* h      = (float*)alloc((size_t)N * D * 4);
    float* acc    = (float*)alloc((size_t)N * D * 4);
    float* alpha  = (float*)alloc((size_t)E * 4);
    unsigned* nmax = (unsigned*)alloc((size_t)N * 4);
    float* denom  = (float*)alloc((size_t)N * 4);
    int* cnt      = (int*)alloc((size_t)R * 4);
    int* offs     = (int*)alloc((size_t)(R + 1) * 4);
    int* cursor   = (int*)alloc((size_t)R * 4);
    int* eids     = (int*)alloc((size_t)E * 4);

    // ---- one-time (per call) prep ----
    hipMemsetAsync(cnt, 0, (size_t)R * 4, stream);
    {
        int total4 = N * D / 4;
        gather_kernel<<<(total4 + 255) / 256, 256, 0, stream>>>(
            (const float4*)emb, entity, (float4*)x0, total4);
    }
    count_kernel<<<(E + 255) / 256, 256, 0, stream>>>(etype, cnt, E);
    scan_kernel<<<1, 512, 0, stream>>>(cnt, offs, cursor, R, E);
    scatter_kernel<<<(E + 255) / 256, 256, 0, stream>>>(etype, cursor, eids, E);

    const int rtiles = (R + 15) / 16;

    // ---- layer 1: x0 -> h (relu) ----
    hipMemsetAsync(nmax, 0, (size_t)N * 4, stream);
    hipMemsetAsync(denom, 0, (size_t)N * 4, stream);
    hipMemsetAsync(acc, 0, (size_t)N * D * 4, stream);
    logit_kernel<<<(E + 3) / 4, 256, 0, stream>>>(x0, w1, src, dst, etype, alpha, nmax, E);
    expden_kernel<<<(E + 255) / 256, 256, 0, stream>>>(alpha, dst, nmax, denom, E);
    wmix_kernel<<<dim3(64, rtiles), 256, 0, stream>>>(att1, basis1, W, R);
    msg_kernel<<<dim3(R, 2), 128, 0, stream>>>(x0, W, eids, offs, src, dst, alpha, denom, acc);
    root_kernel<<<(N + 7) / 8, 128, 0, stream>>>(x0, root1, bias1, acc, h, 1, N);

    // ---- layer 2: h -> out ----
    hipMemsetAsync(nmax, 0, (size_t)N * 4, stream);
    hipMemsetAsync(denom, 0, (size_t)N * 4, stream);
    hipMemsetAsync(out, 0, (size_t)N * D * 4, stream);
    logit_kernel<<<(E + 3) / 4, 256, 0, stream>>>(h, w2, src, dst, etype, alpha, nmax, E);
    expden_kernel<<<(E + 255) / 256, 256, 0, stream>>>(alpha, dst, nmax, denom, E);
    wmix_kernel<<<dim3(64, rtiles), 256, 0, stream>>>(att2, basis2, W, R);
    msg_kernel<<<dim3(R, 2), 128, 0, stream>>>(h, W, eids, offs, src, dst, alpha, denom, out);
    root_kernel<<<(N + 7) / 8, 128, 0, stream>>>(h, root2, bias2, out, out, 0, N);
}

// Round 2
// 434.592 us; speedup vs baseline: 1.0807x; 1.0807x over previous
//
#include <hip/hip_runtime.h>
#include <hip/hip_bf16.h>

#define N_NODES 20000
#define N_EDGES 32768
#define DIM 128
#define N_REL 474
#define N_BASIS 64
#define TILE_E 32
#define MAXCH (N_EDGES / TILE_E + N_REL)   // 1498 upper bound on chunk count
#define RPAD 512                            // padded R for attT

// ---------- helpers ----------
__device__ __forceinline__ unsigned ordf(float f) {
    unsigned u = __float_as_uint(f);
    return (u & 0x80000000u) ? ~u : (u | 0x80000000u);
}
__device__ __forceinline__ float unordf(unsigned u) {
    unsigned v = (u & 0x80000000u) ? (u & 0x7FFFFFFFu) : ~u;
    return __uint_as_float(v);
}

// ---------- x0 = emb[entity] ----------
__global__ void gather_kernel(const float4* __restrict__ emb, const int* __restrict__ entity,
                              float4* __restrict__ x0, int total4) {
    int i = blockIdx.x * blockDim.x + threadIdx.x;
    if (i >= total4) return;
    int n = i >> 5;       // 32 float4 per node
    int rem = i & 31;
    x0[i] = emb[(size_t)entity[n] * 32 + rem];
}

// ---------- edge grouping by relation ----------
__global__ void count_kernel(const int* __restrict__ et, int* __restrict__ cnt, int E) {
    int e = blockIdx.x * blockDim.x + threadIdx.x;
    if (e < E) atomicAdd(&cnt[et[e]], 1);
}

__global__ void scan_kernel(const int* __restrict__ cnt, int* __restrict__ offs,
                            int* __restrict__ cursor, int R, int E) {
    __shared__ int s[512];
    int t = threadIdx.x;
    int v = (t < R) ? cnt[t] : 0;
    s[t] = v;
    __syncthreads();
    for (int d = 1; d < 512; d <<= 1) {
        int add = (t >= d) ? s[t - d] : 0;
        __syncthreads();
        s[t] += add;
        __syncthreads();
    }
    if (t < R) { int excl = s[t] - v; offs[t] = excl; cursor[t] = excl; }
    if (t == 0) offs[R] = E;
}

__global__ void scatter_kernel(const int* __restrict__ et, int* __restrict__ cursor,
                               int* __restrict__ eids, int E) {
    int e = blockIdx.x * blockDim.x + threadIdx.x;
    if (e < E) {
        int p = atomicAdd(&cursor[et[e]], 1);
        eids[p] = e;
    }
}

// ---------- build (relation, 32-edge-chunk) work list ----------
__global__ void chunkbuild_kernel(const int* __restrict__ offs, int* __restrict__ chunk_r,
                                  int* __restrict__ chunk_off, int* __restrict__ nchunks, int R) {
    int r = blockIdx.x * blockDim.x + threadIdx.x;
    if (r >= R) return;
    int s = offs[r], e = offs[r + 1];
    int nc = (e - s + TILE_E - 1) / TILE_E;
    if (nc > 0) {
        int b = atomicAdd(nchunks, nc);
        for (int c = 0; c < nc; c++) { chunk_r[b + c] = r; chunk_off[b + c] = s + c * TILE_E; }
    }
}

// ---------- attT[b][r] = att[r][b], zero-padded to RPAD ----------
__global__ void attT_kernel(const float* __restrict__ att, float* __restrict__ attT, int R) {
    int i = blockIdx.x * 256 + threadIdx.x;
    if (i >= N_BASIS * RPAD) return;
    int b = i >> 9, r = i & (RPAD - 1);
    attT[i] = (r < R) ? att[(size_t)r * N_BASIS + b] : 0.0f;
}

// ---------- per-edge attention logit + segment max ----------
__global__ __launch_bounds__(256) void logit_kernel(const float* __restrict__ x,
                                                    const float* __restrict__ w,
                                                    const int* __restrict__ src,
                                                    const int* __restrict__ dst,
                                                    const int* __restrict__ et,
                                                    float* __restrict__ alpha,
                                                    unsigned* __restrict__ nmax, int E) {
    int wid = (blockIdx.x * 256 + threadIdx.x) >> 6;
    int lane = threadIdx.x & 63;
    if (wid >= E) return;
    int s = src[wid], d = dst[wid], r = et[wid];
    const float* xs_ = x + (size_t)s * DIM;
    const float* xd_ = x + (size_t)d * DIM;
    const float* wr_ = w + (size_t)r * DIM;
    float v = xs_[lane] * wr_[lane] * xd_[lane]
            + xs_[lane + 64] * wr_[lane + 64] * xd_[lane + 64];
    for (int off = 32; off > 0; off >>= 1) v += __shfl_xor(v, off, 64);
    if (lane == 0) {
        alpha[wid] = v;
        atomicMax(&nmax[d], ordf(v));
    }
}

// ---------- exp(alpha - max) + segment denom ----------
__global__ void expden_kernel(float* __restrict__ alpha, const int* __restrict__ dst,
                              const unsigned* __restrict__ nmax, float* __restrict__ denom, int E) {
    int e = blockIdx.x * blockDim.x + threadIdx.x;
    if (e >= E) return;
    int d = dst[e];
    float m = unordf(nmax[d]);
    float a = expf(alpha[e] - m);
    alpha[e] = a;
    atomicAdd(&denom[d], a);
}

// ---------- W[r] = sum_b att[r,b] * basis[b] ; attT is [B][RPAD] ----------
// R-tile of 64 per block; att index is thread-uniform -> scalar loads.
__global__ __launch_bounds__(256) void wmix_kernel(const float* __restrict__ attT,
                                                   const float* __restrict__ basis,
                                                   float* __restrict__ W, int R) {
    int io = blockIdx.x * 256 + threadIdx.x;   // over D*D = 16384
    int r0 = blockIdx.y * 64;                   // 8 tiles cover 474
    float acc[64];
#pragma unroll
    for (int rr = 0; rr < 64; rr++) acc[rr] = 0.0f;
    for (int b = 0; b < N_BASIS; b++) {
        float bv = basis[(size_t)b * (DIM * DIM) + io];
        const float* ap = attT + (size_t)b * RPAD + r0;
#pragma unroll
        for (int rr = 0; rr < 64; rr++) acc[rr] = fmaf(ap[rr], bv, acc[rr]);
    }
#pragma unroll
    for (int rr = 0; rr < 64; rr++) {
        if (r0 + rr < R) W[(size_t)(r0 + rr) * (DIM * DIM) + io] = acc[rr];
    }
}

// ---------- per-edge transform + softmax scale + scatter-add ----------
// one block per 32-edge chunk of a single relation; 128 threads;
// thread tile = 8 edges x 4 cols; x_j in LDS (pad 132 keeps 16B align,
// breaks power-of-2 bank stride); W streamed from global (L1/L2 coalesced).
__global__ __launch_bounds__(128) void msg_kernel(const float* __restrict__ x,
                                                  const float* __restrict__ W,
                                                  const int* __restrict__ chunk_r,
                                                  const int* __restrict__ chunk_off,
                                                  const int* __restrict__ nchunks,
                                                  const int* __restrict__ eids,
                                                  const int* __restrict__ offs,
                                                  const int* __restrict__ src,
                                                  const int* __restrict__ dst,
                                                  const float* __restrict__ ae,
                                                  const float* __restrict__ denom,
                                                  float* __restrict__ out) {
    if ((int)blockIdx.x >= *nchunks) return;
    int r = chunk_r[blockIdx.x];
    int base = chunk_off[blockIdx.x];
    int nE = min(TILE_E, offs[r + 1] - base);
    const float* Wr = W + (size_t)r * (DIM * DIM);

    __shared__ float xj[TILE_E][132];
    __shared__ float cf[TILE_E];
    __shared__ int dd[TILE_E];

    int t = threadIdx.x;
    if (t < TILE_E) {
        if (t < nE) {
            int e = eids[base + t];
            int d_ = dst[e];
            dd[t] = d_;
            cf[t] = ae[e] / denom[d_];
        } else { dd[t] = 0; cf[t] = 0.0f; }
    }
    // stage x_j rows: thread t -> edge t>>2, quarter t&3 (32 floats = 8 float4)
    {
        int e = t >> 2, q = t & 3;
        float4* dp = (float4*)&xj[e][q * 32];
        if (e < nE) {
            const float4* sp = (const float4*)(x + (size_t)src[eids[base + e]] * DIM + q * 32);
#pragma unroll
            for (int p = 0; p < 8; p++) dp[p] = sp[p];
        } else {
            float4 z = make_float4(0.f, 0.f, 0.f, 0.f);
#pragma unroll
            for (int p = 0; p < 8; p++) dp[p] = z;
        }
    }
    __syncthreads();

    int cg = t & 31;        // 32 col groups of 4
    int eg = t >> 5;        // 4 edge groups of 8
    int c0 = cg * 4;
    int e0 = eg * 8;

    float4 acc[8];
#pragma unroll
    for (int j = 0; j < 8; j++) acc[j] = make_float4(0.f, 0.f, 0.f, 0.f);

    for (int k0 = 0; k0 < DIM; k0 += 4) {
        float4 b0 = *(const float4*)&Wr[(k0 + 0) * DIM + c0];
        float4 b1 = *(const float4*)&Wr[(k0 + 1) * DIM + c0];
        float4 b2 = *(const float4*)&Wr[(k0 + 2) * DIM + c0];
        float4 b3 = *(const float4*)&Wr[(k0 + 3) * DIM + c0];
#pragma unroll
        for (int j = 0; j < 8; j++) {
            float4 a = *(const float4*)&xj[e0 + j][k0];
            acc[j].x = fmaf(a.x, b0.x, fmaf(a.y, b1.x, fmaf(a.z, b2.x, fmaf(a.w, b3.x, acc[j].x))));
            acc[j].y = fmaf(a.x, b0.y, fmaf(a.y, b1.y, fmaf(a.z, b2.y, fmaf(a.w, b3.y, acc[j].y))));
            acc[j].z = fmaf(a.x, b0.z, fmaf(a.y, b1.z, fmaf(a.z, b2.z, fmaf(a.w, b3.z, acc[j].z))));
            acc[j].w = fmaf(a.x, b0.w, fmaf(a.y, b1.w, fmaf(a.z, b2.w, fmaf(a.w, b3.w, acc[j].w))));
        }
    }

#pragma unroll
    for (int j = 0; j < 8; j++) {
        int e = e0 + j;
        if (e < nE) {
            float c = cf[e];
            float* op = out + (size_t)dd[e] * DIM + c0;
            atomicAdd(op + 0, c * acc[j].x);
            atomicAdd(op + 1, c * acc[j].y);
            atomicAdd(op + 2, c * acc[j].z);
            atomicAdd(op + 3, c * acc[j].w);
        }
    }
}

// ---------- out = acc + x @ root + bias (optional relu) ----------
__global__ __launch_bounds__(128) void root_kernel(const float* __restrict__ x,
                                                   const float* __restrict__ rootM,
                                                   const float* __restrict__ bias,
                                                   const float* __restrict__ acc,
                                                   float* __restrict__ out, int relu, int N) {
    int n0 = blockIdx.x * 8;
    int o = threadIdx.x;
    __shared__ float xs[8][DIM];
#pragma unroll
    for (int k = 0; k < 8; k++) {
        int n = n0 + k;
        if (n < N) xs[k][o] = x[(size_t)n * DIM + o];
    }
    __syncthreads();
    float a[8] = {0, 0, 0, 0, 0, 0, 0, 0};
    for (int i = 0; i < DIM; i++) {
        float rv = rootM[i * DIM + o];
#pragma unroll
        for (int k = 0; k < 8; k++) a[k] = fmaf(xs[k][i], rv, a[k]);
    }
    float bo = bias[o];
#pragma unroll
    for (int k = 0; k < 8; k++) {
        int n = n0 + k;
        if (n < N) {
            float v = acc[(size_t)n * DIM + o] + a[k] + bo;
            if (relu) v = fmaxf(v, 0.f);
            out[(size_t)n * DIM + o] = v;
        }
    }
}

extern "C" void kernel_launch(void* const* d_in, const int* in_sizes, int n_in,
                              void* d_out, int out_size, void* d_ws, size_t ws_size,
                              hipStream_t stream) {
    const int N = N_NODES, E = N_EDGES, D = DIM, R = N_REL;

    const int* entity = (const int*)d_in[0];
    const int* eidx   = (const int*)d_in[1];
    const int* src    = eidx;
    const int* dst    = eidx + E;
    const int* etype  = (const int*)d_in[2];
    const float* emb  = (const float*)d_in[3];
    const float* basis1 = (const float*)d_in[4];
    const float* att1   = (const float*)d_in[5];
    const float* w1     = (const float*)d_in[6];
    const float* root1  = (const float*)d_in[7];
    const float* bias1  = (const float*)d_in[8];
    const float* basis2 = (const float*)d_in[9];
    const float* att2   = (const float*)d_in[10];
    const float* w2     = (const float*)d_in[11];
    const float* root2  = (const float*)d_in[12];
    const float* bias2  = (const float*)d_in[13];
    float* out = (float*)d_out;

    size_t off = 0;
    auto alloc = [&](size_t bytes) -> void* {
        void* p = (char*)d_ws + off;
        off += (bytes + 255) & ~(size_t)255;
        return p;
    };
    float* W      = (float*)alloc((size_t)R * D * D * 4);
    float* x0     = (float*)alloc((size_t)N * D * 4);
    float* h      = (float*)alloc((size_t)N * D * 4);
    float* acc    = (float*)alloc((size_t)N * D * 4);
    float* alpha  = (float*)alloc((size_t)E * 4);
    unsigned* nmax = (unsigned*)alloc((size_t)N * 4);
    float* denom  = (float*)alloc((size_t)N * 4);
    int* cnt      = (int*)alloc((size_t)R * 4);
    int* offs     = (int*)alloc((size_t)(R + 1) * 4);
    int* cursor   = (int*)alloc((size_t)R * 4);
    int* eids     = (int*)alloc((size_t)E * 4);
    int* chunk_r  = (int*)alloc((size_t)MAXCH * 4);
    int* chunk_o  = (int*)alloc((size_t)MAXCH * 4);
    int* nchunks  = (int*)alloc(256);
    float* attT   = (float*)alloc((size_t)N_BASIS * RPAD * 4);

    // ---- per-call prep ----
    hipMemsetAsync(cnt, 0, (size_t)R * 4, stream);
    hipMemsetAsync(nchunks, 0, 4, stream);
    {
        int total4 = N * D / 4;
        gather_kernel<<<(total4 + 255) / 256, 256, 0, stream>>>(
            (const float4*)emb, entity, (float4*)x0, total4);
    }
    count_kernel<<<(E + 255) / 256, 256, 0, stream>>>(etype, cnt, E);
    scan_kernel<<<1, 512, 0, stream>>>(cnt, offs, cursor, R, E);
    scatter_kernel<<<(E + 255) / 256, 256, 0, stream>>>(etype, cursor, eids, E);
    chunkbuild_kernel<<<(R + 255) / 256, 256, 0, stream>>>(offs, chunk_r, chunk_o, nchunks, R);

    // ---- layer 1: x0 -> h (relu) ----
    hipMemsetAsync(nmax, 0, (size_t)N * 4, stream);
    hipMemsetAsync(denom, 0, (size_t)N * 4, stream);
    hipMemsetAsync(acc, 0, (size_t)N * D * 4, stream);
    attT_kernel<<<(N_BASIS * RPAD + 255) / 256, 256, 0, stream>>>(att1, attT, R);
    logit_kernel<<<(E + 3) / 4, 256, 0, stream>>>(x0, w1, src, dst, etype, alpha, nmax, E);
    expden_kernel<<<(E + 255) / 256, 256, 0, stream>>>(alpha, dst, nmax, denom, E);
    wmix_kernel<<<dim3(64, 8), 256, 0, stream>>>(attT, basis1, W, R);
    msg_kernel<<<MAXCH, 128, 0, stream>>>(x0, W, chunk_r, chunk_o, nchunks,
                                          eids, offs, src, dst, alpha, denom, acc);
    root_kernel<<<(N + 7) / 8, 128, 0, stream>>>(x0, root1, bias1, acc, h, 1, N);

    // ---- layer 2: h -> out ----
    hipMemsetAsync(nmax, 0, (size_t)N * 4, stream);
    hipMemsetAsync(denom, 0, (size_t)N * 4, stream);
    hipMemsetAsync(out, 0, (size_t)N * D * 4, stream);
    attT_kernel<<<(N_BASIS * RPAD + 255) / 256, 256, 0, stream>>>(att2, attT, R);
    logit_kernel<<<(E + 3) / 4, 256, 0, stream>>>(h, w2, src, dst, etype, alpha, nmax, E);
    expden_kernel<<<(E + 255) / 256, 256, 0, stream>>>(alpha, dst, nmax, denom, E);
    wmix_kernel<<<dim3(64, 8), 256, 0, stream>>>(attT, basis2, W, R);
    msg_kernel<<<MAXCH, 128, 0, stream>>>(h, W, chunk_r, chunk_o, nchunks,
                                          eids, offs, src, dst, alpha, denom, out);
    root_kernel<<<(N + 7) / 8, 128, 0, stream>>>(h, root2, bias2, out, out, 0, N);
}

// Round 4
// 311.159 us; speedup vs baseline: 1.5094x; 1.3967x over previous
//
#include <hip/hip_runtime.h>
#include <hip/hip_bf16.h>

#define N_NODES 20000
#define N_EDGES 32768
#define DIM 128
#define N_REL 474
#define N_BASIS 64
#define TILE_E 32
#define MAXCH (N_EDGES / TILE_E + N_REL)   // 1498 upper bound on chunk count

typedef __bf16 bf16x8 __attribute__((ext_vector_type(8)));
typedef float f32x4 __attribute__((ext_vector_type(4)));

// ---------- helpers ----------
__device__ __forceinline__ unsigned ordf(float f) {
    unsigned u = __float_as_uint(f);
    return (u & 0x80000000u) ? ~u : (u | 0x80000000u);
}
__device__ __forceinline__ float unordf(unsigned u) {
    unsigned v = (u & 0x80000000u) ? (u & 0x7FFFFFFFu) : ~u;
    return __uint_as_float(v);
}
__device__ __forceinline__ unsigned short f2b(float f) {   // RNE fp32 -> bf16 bits
    unsigned u = __float_as_uint(f);
    unsigned r = (u + 0x7FFFu + ((u >> 16) & 1u)) >> 16;
    return (unsigned short)r;
}
__device__ __forceinline__ float b2f(unsigned short s) {
    return __uint_as_float(((unsigned)s) << 16);
}
__device__ __forceinline__ __bf16 u2b(unsigned short u) {
    union { unsigned short u; __bf16 b; } c; c.u = u; return c.b;
}

// ---------- xb = bf16(emb[entity]) ----------
__global__ void gather_kernel(const float4* __restrict__ emb, const int* __restrict__ entity,
                              ushort4* __restrict__ xb, int total4) {
    int i = blockIdx.x * blockDim.x + threadIdx.x;
    if (i >= total4) return;
    int n = i >> 5;       // 32 float4 per node
    int rem = i & 31;
    float4 v = emb[(size_t)entity[n] * 32 + rem];
    ushort4 s;
    s.x = f2b(v.x); s.y = f2b(v.y); s.z = f2b(v.z); s.w = f2b(v.w);
    xb[i] = s;
}

// ---------- edge grouping by relation ----------
__global__ void count_kernel(const int* __restrict__ et, int* __restrict__ cnt, int E) {
    int e = blockIdx.x * blockDim.x + threadIdx.x;
    if (e < E) atomicAdd(&cnt[et[e]], 1);
}

__global__ void scan_kernel(const int* __restrict__ cnt, int* __restrict__ offs,
                            int* __restrict__ cursor, int R, int E) {
    __shared__ int s[512];
    int t = threadIdx.x;
    int v = (t < R) ? cnt[t] : 0;
    s[t] = v;
    __syncthreads();
    for (int d = 1; d < 512; d <<= 1) {
        int add = (t >= d) ? s[t - d] : 0;
        __syncthreads();
        s[t] += add;
        __syncthreads();
    }
    if (t < R) { int excl = s[t] - v; offs[t] = excl; cursor[t] = excl; }
    if (t == 0) offs[R] = E;
}

__global__ void scatter_kernel(const int* __restrict__ et, int* __restrict__ cursor,
                               int* __restrict__ eids, int E) {
    int e = blockIdx.x * blockDim.x + threadIdx.x;
    if (e < E) {
        int p = atomicAdd(&cursor[et[e]], 1);
        eids[p] = e;
    }
}

// ---------- build (relation, 32-edge-chunk) work list ----------
__global__ void chunkbuild_kernel(const int* __restrict__ offs, int* __restrict__ chunk_r,
                                  int* __restrict__ chunk_off, int* __restrict__ nchunks, int R) {
    int r = blockIdx.x * blockDim.x + threadIdx.x;
    if (r >= R) return;
    int s = offs[r], e = offs[r + 1];
    int nc = (e - s + TILE_E - 1) / TILE_E;
    if (nc > 0) {
        int b = atomicAdd(nchunks, nc);
        for (int c = 0; c < nc; c++) { chunk_r[b + c] = r; chunk_off[b + c] = s + c * TILE_E; }
    }
}

// ---------- per-edge attention logit + segment max (bf16 x, fp32 w) ----------
__global__ __launch_bounds__(256) void logit_kernel(const unsigned short* __restrict__ xb,
                                                    const float* __restrict__ w,
                                                    const int* __restrict__ src,
                                                    const int* __restrict__ dst,
                                                    const int* __restrict__ et,
                                                    float* __restrict__ alpha,
                                                    unsigned* __restrict__ nmax, int E) {
    int wid = (blockIdx.x * 256 + threadIdx.x) >> 6;
    int lane = threadIdx.x & 63;
    if (wid >= E) return;
    int s = src[wid], d = dst[wid], r = et[wid];
    unsigned ax = ((const unsigned*)(xb + (size_t)s * DIM))[lane];
    unsigned bx = ((const unsigned*)(xb + (size_t)d * DIM))[lane];
    float2 wv = ((const float2*)(w + (size_t)r * DIM))[lane];
    float v = b2f((unsigned short)(ax & 0xFFFF)) * wv.x * b2f((unsigned short)(bx & 0xFFFF))
            + b2f((unsigned short)(ax >> 16)) * wv.y * b2f((unsigned short)(bx >> 16));
    for (int off = 32; off > 0; off >>= 1) v += __shfl_xor(v, off, 64);
    if (lane == 0) {
        alpha[wid] = v;
        atomicMax(&nmax[d], ordf(v));
    }
}

// ---------- exp(alpha - max) + segment denom ----------
__global__ void expden_kernel(float* __restrict__ alpha, const int* __restrict__ dst,
                              const unsigned* __restrict__ nmax, float* __restrict__ denom, int E) {
    int e = blockIdx.x * blockDim.x + threadIdx.x;
    if (e >= E) return;
    int d = dst[e];
    float m = unordf(nmax[d]);
    float a = expf(alpha[e] - m);
    alpha[e] = a;
    atomicAdd(&denom[d], a);
}

// ---------- W[r][k][o] (bf16) = sum_b att[r,b] * basis[b][k][o] ----------
__global__ __launch_bounds__(256) void wmix_kernel(const float* __restrict__ att,
                                                   const float* __restrict__ basis,
                                                   unsigned short* __restrict__ W, int R) {
    int t = threadIdx.x;
    int io = blockIdx.x * 512 + t * 2;
    int r0 = blockIdx.y * 64;
    __shared__ float satt[64 * 64];    // [b][rr]
    for (int idx = t; idx < 4096; idx += 256) {
        int rr = idx >> 6, b = idx & 63;
        satt[b * 64 + rr] = (r0 + rr < R) ? att[(size_t)(r0 + rr) * N_BASIS + b] : 0.f;
    }
    __syncthreads();
    float2 acc[64];
#pragma unroll
    for (int rr = 0; rr < 64; rr++) acc[rr] = make_float2(0.f, 0.f);
    for (int b = 0; b < N_BASIS; b++) {
        float2 bv = *(const float2*)(basis + (size_t)b * (DIM * DIM) + io);
        const float4* ap4 = (const float4*)&satt[b * 64];
#pragma unroll
        for (int rq = 0; rq < 16; rq++) {
            float4 a4 = ap4[rq];
            int rr = rq * 4;
            acc[rr + 0].x = fmaf(a4.x, bv.x, acc[rr + 0].x); acc[rr + 0].y = fmaf(a4.x, bv.y, acc[rr + 0].y);
            acc[rr + 1].x = fmaf(a4.y, bv.x, acc[rr + 1].x); acc[rr + 1].y = fmaf(a4.y, bv.y, acc[rr + 1].y);
            acc[rr + 2].x = fmaf(a4.z, bv.x, acc[rr + 2].x); acc[rr + 2].y = fmaf(a4.z, bv.y, acc[rr + 2].y);
            acc[rr + 3].x = fmaf(a4.w, bv.x, acc[rr + 3].x); acc[rr + 3].y = fmaf(a4.w, bv.y, acc[rr + 3].y);
        }
    }
#pragma unroll
    for (int rr = 0; rr < 64; rr++) {
        if (r0 + rr < R) {
            unsigned pk = (unsigned)f2b(acc[rr].x) | ((unsigned)f2b(acc[rr].y) << 16);
            *(unsigned*)&W[(size_t)(r0 + rr) * (DIM * DIM) + io] = pk;
        }
    }
}

// ---------- msg: per 32-edge chunk, (32x128)@(128x128) via MFMA bf16 ----------
__global__ __launch_bounds__(256) void msg_kernel(const unsigned short* __restrict__ xb,
                                                  const unsigned short* __restrict__ W,
                                                  const int* __restrict__ chunk_r,
                                                  const int* __restrict__ chunk_off,
                                                  const int* __restrict__ nchunks,
                                                  const int* __restrict__ eids,
                                                  const int* __restrict__ offs,
                                                  const int* __restrict__ src,
                                                  const int* __restrict__ dst,
                                                  const float* __restrict__ ae,
                                                  const float* __restrict__ denom,
                                                  float* __restrict__ outacc) {
    if ((int)blockIdx.x >= *nchunks) return;
    int r = chunk_r[blockIdx.x];
    int base = chunk_off[blockIdx.x];
    int nE = min(TILE_E, offs[r + 1] - base);
    const unsigned short* Wr = W + (size_t)r * (DIM * DIM);

    __shared__ unsigned short wt[128 * 136];   // [k][o] rows padded to 272B
    __shared__ unsigned short xjf[4096];       // A-frag order: ((rt*4+kb)*64+lane)*8+j
    __shared__ float scf[TILE_E];
    __shared__ int sdd[TILE_E];

    int t = threadIdx.x;
    if (t < TILE_E) {
        if (t < nE) {
            int e = eids[base + t];
            int d_ = dst[e];
            sdd[t] = d_;
            scf[t] = ae[e] / denom[d_];
        } else { sdd[t] = 0; scf[t] = 0.f; }
    }
    // stage x_src rows in A-frag order: 32 edges x 16 octets = 512 int4 chunks
#pragma unroll
    for (int p = 0; p < 2; p++) {
        int c = t + 256 * p;
        int e = c >> 4, oct = c & 15;
        int kb = oct >> 2, q = oct & 3, rt = e >> 4, m = e & 15;
        int4 v = make_int4(0, 0, 0, 0);
        if (e < nE)
            v = *(const int4*)(xb + (size_t)src[eids[base + e]] * DIM + oct * 8);
        *(int4*)&xjf[((rt * 4 + kb) * 64 + q * 16 + m) * 8] = v;
    }
    // stage W tile: 128 rows x 16 octets = 2048 int4 chunks
#pragma unroll
    for (int p = 0; p < 8; p++) {
        int c = t + 256 * p;
        int k = c >> 4, oct = c & 15;
        int4 v = *(const int4*)(Wr + k * DIM + oct * 8);
        *(int4*)&wt[k * 136 + oct * 8] = v;
    }
    __syncthreads();

    int w = t >> 6, l = t & 63, n = l & 15, q = l >> 4;
    f32x4 acc[2][2] = {};                       // [ct-local][rt]
#pragma unroll
    for (int kb = 0; kb < 4; kb++) {
        bf16x8 a0 = *(const bf16x8*)&xjf[((0 * 4 + kb) * 64 + l) * 8];
        bf16x8 a1 = *(const bf16x8*)&xjf[((1 * 4 + kb) * 64 + l) * 8];
        int kbase = kb * 32 + q * 8;
#pragma unroll
        for (int c = 0; c < 2; c++) {
            int ob = (w * 2 + c) * 16 + n;
            bf16x8 b;
#pragma unroll
            for (int j = 0; j < 8; j++) b[j] = u2b(wt[(kbase + j) * 136 + ob]);
            acc[c][0] = __builtin_amdgcn_mfma_f32_16x16x32_bf16(a0, b, acc[c][0], 0, 0, 0);
            acc[c][1] = __builtin_amdgcn_mfma_f32_16x16x32_bf16(a1, b, acc[c][1], 0, 0, 0);
        }
    }
#pragma unroll
    for (int c = 0; c < 2; c++) {
        int col = (w * 2 + c) * 16 + n;
#pragma unroll
        for (int rt = 0; rt < 2; rt++) {
#pragma unroll
            for (int rg = 0; rg < 4; rg++) {
                int e = rt * 16 + q * 4 + rg;
                if (e < nE)
                    atomicAdd(&outacc[(size_t)sdd[e] * DIM + col], scf[e] * acc[c][rt][rg]);
            }
        }
    }
}

// ---------- root: out = acc + x @ root + bias via MFMA; mode 1 = relu+bf16, 0 = fp32 ----------
__global__ __launch_bounds__(256) void root_kernel(const unsigned short* __restrict__ xb,
                                                   const float* __restrict__ rootM,
                                                   const float* __restrict__ bias,
                                                   const float* __restrict__ accbuf,
                                                   unsigned short* __restrict__ outb,
                                                   float* __restrict__ outf,
                                                   int mode, int N) {
    int n0 = blockIdx.x * 64;
    __shared__ unsigned short wt[128 * 136];   // root bf16 [k][o] pad
    __shared__ unsigned short xrf[8192];       // 64 rows A-frag order (4 rt)
    int t = threadIdx.x;
    // stage x rows: 64 rows x 16 octets = 1024 int4 chunks
#pragma unroll
    for (int p = 0; p < 4; p++) {
        int c = t + 256 * p;
        int ri = c >> 4, oct = c & 15;
        int kb = oct >> 2, q = oct & 3, rt = ri >> 4, m = ri & 15;
        int4 v = make_int4(0, 0, 0, 0);
        int row = n0 + ri;
        if (row < N) v = *(const int4*)(xb + (size_t)row * DIM + oct * 8);
        *(int4*)&xrf[((rt * 4 + kb) * 64 + q * 16 + m) * 8] = v;
    }
    // stage root fp32 -> bf16: 4096 float4 chunks
#pragma unroll
    for (int p = 0; p < 16; p++) {
        int c = t + 256 * p;
        int k = c >> 5, of = c & 31;
        float4 v = *(const float4*)(rootM + k * DIM + of * 4);
        ushort4 s;
        s.x = f2b(v.x); s.y = f2b(v.y); s.z = f2b(v.z); s.w = f2b(v.w);
        *(ushort4*)&wt[k * 136 + of * 4] = s;
    }
    __syncthreads();

    int w = t >> 6, l = t & 63, n = l & 15, q = l >> 4;
    f32x4 acc[2][4] = {};
#pragma unroll
    for (int kb = 0; kb < 4; kb++) {
        bf16x8 a[4];
#pragma unroll
        for (int rt = 0; rt < 4; rt++) a[rt] = *(const bf16x8*)&xrf[((rt * 4 + kb) * 64 + l) * 8];
        int kbase = kb * 32 + q * 8;
#pragma unroll
        for (int c = 0; c < 2; c++) {
            int ob = (w * 2 + c) * 16 + n;
            bf16x8 b;
#pragma unroll
            for (int j = 0; j < 8; j++) b[j] = u2b(wt[(kbase + j) * 136 + ob]);
#pragma unroll
            for (int rt = 0; rt < 4; rt++)
                acc[c][rt] = __builtin_amdgcn_mfma_f32_16x16x32_bf16(a[rt], b, acc[c][rt], 0, 0, 0);
        }
    }
#pragma unroll
    for (int c = 0; c < 2; c++) {
        int col = (w * 2 + c) * 16 + n;
        float bo = bias[col];
#pragma unroll
        for (int rt = 0; rt < 4; rt++) {
#pragma unroll
            for (int rg = 0; rg < 4; rg++) {
                int row = n0 + rt * 16 + q * 4 + rg;
                if (row < N) {
                    float v = accbuf[(size_t)row * DIM + col] + acc[c][rt][rg] + bo;
                    if (mode) {
                        v = fmaxf(v, 0.f);
                        outb[(size_t)row * DIM + col] = f2b(v);
                    } else {
                        outf[(size_t)row * DIM + col] = v;
                    }
                }
            }
        }
    }
}

extern "C" void kernel_launch(void* const* d_in, const int* in_sizes, int n_in,
                              void* d_out, int out_size, void* d_ws, size_t ws_size,
                              hipStream_t stream) {
    const int N = N_NODES, E = N_EDGES, R = N_REL;

    const int* entity = (const int*)d_in[0];
    const int* eidx   = (const int*)d_in[1];
    const int* src    = eidx;
    const int* dst    = eidx + E;
    const int* etype  = (const int*)d_in[2];
    const float* emb  = (const float*)d_in[3];
    const float* basis1 = (const float*)d_in[4];
    const float* att1   = (const float*)d_in[5];
    const float* w1     = (const float*)d_in[6];
    const float* root1  = (const float*)d_in[7];
    const float* bias1  = (const float*)d_in[8];
    const float* basis2 = (const float*)d_in[9];
    const float* att2   = (const float*)d_in[10];
    const float* w2     = (const float*)d_in[11];
    const float* root2  = (const float*)d_in[12];
    const float* bias2  = (const float*)d_in[13];
    float* out = (float*)d_out;

    size_t off = 0;
    auto alloc = [&](size_t bytes) -> void* {
        void* p = (char*)d_ws + off;
        off += (bytes + 255) & ~(size_t)255;
        return p;
    };
    unsigned short* W  = (unsigned short*)alloc((size_t)R * DIM * DIM * 2);
    unsigned short* xb = (unsigned short*)alloc((size_t)N * DIM * 2);
    unsigned short* hb = (unsigned short*)alloc((size_t)N * DIM * 2);
    float* seg    = (float*)alloc((size_t)N * (2 + DIM) * 4);   // nmax | denom | acc
    unsigned* nmax = (unsigned*)seg;
    float* denom  = seg + N;
    float* acc    = seg + 2 * N;
    float* alpha  = (float*)alloc((size_t)E * 4);
    int* meta     = (int*)alloc((size_t)(R + 1) * 4);   // cnt | nchunks
    int* cnt      = meta;
    int* nchunks  = meta + R;
    int* offs     = (int*)alloc((size_t)(R + 1) * 4);
    int* cursor   = (int*)alloc((size_t)R * 4);
    int* eids     = (int*)alloc((size_t)E * 4);
    int* chunk_r  = (int*)alloc((size_t)MAXCH * 4);
    int* chunk_o  = (int*)alloc((size_t)MAXCH * 4);

    // ---- prep ----
    hipMemsetAsync(meta, 0, (size_t)(R + 1) * 4, stream);
    {
        int total4 = N * DIM / 4;
        gather_kernel<<<(total4 + 255) / 256, 256, 0, stream>>>(
            (const float4*)emb, entity, (ushort4*)xb, total4);
    }
    count_kernel<<<(E + 255) / 256, 256, 0, stream>>>(etype, cnt, E);
    scan_kernel<<<1, 512, 0, stream>>>(cnt, offs, cursor, R, E);
    scatter_kernel<<<(E + 255) / 256, 256, 0, stream>>>(etype, cursor, eids, E);
    chunkbuild_kernel<<<(R + 255) / 256, 256, 0, stream>>>(offs, chunk_r, chunk_o, nchunks, R);

    // ---- layer 1: xb -> hb (relu, bf16) ----
    hipMemsetAsync(seg, 0, (size_t)N * (2 + DIM) * 4, stream);
    logit_kernel<<<E / 4, 256, 0, stream>>>(xb, w1, src, dst, etype, alpha, nmax, E);
    expden_kernel<<<(E + 255) / 256, 256, 0, stream>>>(alpha, dst, nmax, denom, E);
    wmix_kernel<<<dim3(32, 8), 256, 0, stream>>>(att1, basis1, W, R);
    msg_kernel<<<MAXCH, 256, 0, stream>>>(xb, W, chunk_r, chunk_o, nchunks,
                                          eids, offs, src, dst, alpha, denom, acc);
    root_kernel<<<(N + 63) / 64, 256, 0, stream>>>(xb, root1, bias1, acc, hb, nullptr, 1, N);

    // ---- layer 2: hb -> out (fp32) ----
    hipMemsetAsync(seg, 0, (size_t)N * (2 + DIM) * 4, stream);
    logit_kernel<<<E / 4, 256, 0, stream>>>(hb, w2, src, dst, etype, alpha, nmax, E);
    expden_kernel<<<(E + 255) / 256, 256, 0, stream>>>(alpha, dst, nmax, denom, E);
    wmix_kernel<<<dim3(32, 8), 256, 0, stream>>>(att2, basis2, W, R);
    msg_kernel<<<MAXCH, 256, 0, stream>>>(hb, W, chunk_r, chunk_o, nchunks,
                                          eids, offs, src, dst, alpha, denom, acc);
    root_kernel<<<(N + 63) / 64, 256, 0, stream>>>(hb, root2, bias2, acc, nullptr, out, 0, N);
}

// Round 5
// 264.573 us; speedup vs baseline: 1.7752x; 1.1761x over previous
//
#include <hip/hip_runtime.h>
#include <hip/hip_bf16.h>

#define N_NODES 20000
#define N_EDGES 32768
#define DIM 128
#define N_REL 474
#define N_BASIS 64
#define TILE_E 32
#define MAXCH (N_EDGES / TILE_E + N_REL)   // 1498 upper bound on chunk count
#define WSTRIDE 260                         // LDS row stride (shorts) for wmix staging

typedef __bf16 bf16x8 __attribute__((ext_vector_type(8)));
typedef float f32x4 __attribute__((ext_vector_type(4)));

// ---------- helpers ----------
__device__ __forceinline__ unsigned ordf(float f) {
    unsigned u = __float_as_uint(f);
    return (u & 0x80000000u) ? ~u : (u | 0x80000000u);
}
__device__ __forceinline__ float unordf(unsigned u) {
    unsigned v = (u & 0x80000000u) ? (u & 0x7FFFFFFFu) : ~u;
    return __uint_as_float(v);
}
__device__ __forceinline__ unsigned short f2b(float f) {   // RNE fp32 -> bf16 bits
    unsigned u = __float_as_uint(f);
    unsigned r = (u + 0x7FFFu + ((u >> 16) & 1u)) >> 16;
    return (unsigned short)r;
}
__device__ __forceinline__ float b2f(unsigned short s) {
    return __uint_as_float(((unsigned)s) << 16);
}
__device__ __forceinline__ __bf16 u2b(unsigned short u) {
    union { unsigned short u; __bf16 b; } c; c.u = u; return c.b;
}

// ---------- xb = bf16(emb[entity]) ----------
__global__ void gather_kernel(const float4* __restrict__ emb, const int* __restrict__ entity,
                              ushort4* __restrict__ xb, int total4) {
    int i = blockIdx.x * blockDim.x + threadIdx.x;
    if (i >= total4) return;
    int n = i >> 5;       // 32 float4 per node
    int rem = i & 31;
    float4 v = emb[(size_t)entity[n] * 32 + rem];
    ushort4 s;
    s.x = f2b(v.x); s.y = f2b(v.y); s.z = f2b(v.z); s.w = f2b(v.w);
    xb[i] = s;
}

// ---------- edge grouping by relation ----------
__global__ void count_kernel(const int* __restrict__ et, int* __restrict__ cnt, int E) {
    int e = blockIdx.x * blockDim.x + threadIdx.x;
    if (e < E) atomicAdd(&cnt[et[e]], 1);
}

__global__ void scan_kernel(const int* __restrict__ cnt, int* __restrict__ offs,
                            int* __restrict__ cursor, int R, int E) {
    __shared__ int s[512];
    int t = threadIdx.x;
    int v = (t < R) ? cnt[t] : 0;
    s[t] = v;
    __syncthreads();
    for (int d = 1; d < 512; d <<= 1) {
        int add = (t >= d) ? s[t - d] : 0;
        __syncthreads();
        s[t] += add;
        __syncthreads();
    }
    if (t < R) { int excl = s[t] - v; offs[t] = excl; cursor[t] = excl; }
    if (t == 0) offs[R] = E;
}

__global__ void scatter_kernel(const int* __restrict__ et, int* __restrict__ cursor,
                               int* __restrict__ eids, int E) {
    int e = blockIdx.x * blockDim.x + threadIdx.x;
    if (e < E) {
        int p = atomicAdd(&cursor[et[e]], 1);
        eids[p] = e;
    }
}

// ---------- build (relation, 32-edge-chunk) work list ----------
__global__ void chunkbuild_kernel(const int* __restrict__ offs, int* __restrict__ chunk_r,
                                  int* __restrict__ chunk_off, int* __restrict__ nchunks, int R) {
    int r = blockIdx.x * blockDim.x + threadIdx.x;
    if (r >= R) return;
    int s = offs[r], e = offs[r + 1];
    int nc = (e - s + TILE_E - 1) / TILE_E;
    if (nc > 0) {
        int b = atomicAdd(nchunks, nc);
        for (int c = 0; c < nc; c++) { chunk_r[b + c] = r; chunk_off[b + c] = s + c * TILE_E; }
    }
}

// ---------- per-edge attention logit + segment max (bf16 x, fp32 w) ----------
__global__ __launch_bounds__(256) void logit_kernel(const unsigned short* __restrict__ xb,
                                                    const float* __restrict__ w,
                                                    const int* __restrict__ src,
                                                    const int* __restrict__ dst,
                                                    const int* __restrict__ et,
                                                    float* __restrict__ alpha,
                                                    unsigned* __restrict__ nmax, int E) {
    int wid = (blockIdx.x * 256 + threadIdx.x) >> 6;
    int lane = threadIdx.x & 63;
    if (wid >= E) return;
    int s = src[wid], d = dst[wid], r = et[wid];
    unsigned ax = ((const unsigned*)(xb + (size_t)s * DIM))[lane];
    unsigned bx = ((const unsigned*)(xb + (size_t)d * DIM))[lane];
    float2 wv = ((const float2*)(w + (size_t)r * DIM))[lane];
    float v = b2f((unsigned short)(ax & 0xFFFF)) * wv.x * b2f((unsigned short)(bx & 0xFFFF))
            + b2f((unsigned short)(ax >> 16)) * wv.y * b2f((unsigned short)(bx >> 16));
    for (int off = 32; off > 0; off >>= 1) v += __shfl_xor(v, off, 64);
    if (lane == 0) {
        alpha[wid] = v;
        atomicMax(&nmax[d], ordf(v));
    }
}

// ---------- exp(alpha - max) + segment denom ----------
__global__ void expden_kernel(float* __restrict__ alpha, const int* __restrict__ dst,
                              const unsigned* __restrict__ nmax, float* __restrict__ denom, int E) {
    int e = blockIdx.x * blockDim.x + threadIdx.x;
    if (e >= E) return;
    int d = dst[e];
    float m = unordf(nmax[d]);
    float a = expf(alpha[e] - m);
    alpha[e] = a;
    atomicAdd(&denom[d], a);
}

// ---------- W = att @ basis via MFMA: [R,64] @ [64, D*D] -> bf16 ----------
// grid (64 io-chunks of 256, 30 r-tiles of 16), 256 thr.
// basis chunk staged fp32->bf16 in LDS [k][io], row stride 260 shorts
// (q-octet bank offsets {0,16} -> 2-way sharing, free per m136).
__global__ __launch_bounds__(256) void wmix_kernel(const float* __restrict__ att,
                                                   const float* __restrict__ basis,
                                                   unsigned short* __restrict__ W, int R) {
    int io0 = blockIdx.x * 256;
    int r0 = blockIdx.y * 16;
    __shared__ unsigned short bt[64 * WSTRIDE];
    int t = threadIdx.x;
    // stage 64 rows x 256 cols: 4096 float4 chunks (k uniform per wave-iter)
#pragma unroll
    for (int p = 0; p < 16; p++) {
        int c = t + 256 * p;
        int k = c >> 6, of = c & 63;
        float4 v = *(const float4*)(basis + (size_t)k * (DIM * DIM) + io0 + of * 4);
        ushort4 s;
        s.x = f2b(v.x); s.y = f2b(v.y); s.z = f2b(v.z); s.w = f2b(v.w);
        *(ushort4*)&bt[k * WSTRIDE + of * 4] = s;
    }
    __syncthreads();

    int w = t >> 6, l = t & 63, n = l & 15, q = l >> 4;
    int rm = min(r0 + n, R - 1);            // A row (clamped; stores guarded)
    f32x4 acc[4] = {};
#pragma unroll
    for (int kb = 0; kb < 2; kb++) {
        int kbase = kb * 32 + q * 8;
        const float* ap = att + (size_t)rm * N_BASIS + kbase;
        bf16x8 a;
#pragma unroll
        for (int j = 0; j < 8; j++) a[j] = u2b(f2b(ap[j]));
#pragma unroll
        for (int c = 0; c < 4; c++) {
            int ob = w * 64 + c * 16 + n;
            bf16x8 b;
#pragma unroll
            for (int j = 0; j < 8; j++) b[j] = u2b(bt[(kbase + j) * WSTRIDE + ob]);
            acc[c] = __builtin_amdgcn_mfma_f32_16x16x32_bf16(a, b, acc[c], 0, 0, 0);
        }
    }
#pragma unroll
    for (int c = 0; c < 4; c++) {
        int col = io0 + w * 64 + c * 16 + n;
#pragma unroll
        for (int rg = 0; rg < 4; rg++) {
            int r = r0 + q * 4 + rg;
            if (r < R) W[(size_t)r * (DIM * DIM) + col] = f2b(acc[c][rg]);
        }
    }
}

// ---------- msg: per 32-edge chunk, (32x128)@(128x128) via MFMA bf16 ----------
__global__ __launch_bounds__(256) void msg_kernel(const unsigned short* __restrict__ xb,
                                                  const unsigned short* __restrict__ W,
                                                  const int* __restrict__ chunk_r,
                                                  const int* __restrict__ chunk_off,
                                                  const int* __restrict__ nchunks,
                                                  const int* __restrict__ eids,
                                                  const int* __restrict__ offs,
                                                  const int* __restrict__ src,
                                                  const int* __restrict__ dst,
                                                  const float* __restrict__ ae,
                                                  const float* __restrict__ denom,
                                                  float* __restrict__ outacc) {
    if ((int)blockIdx.x >= *nchunks) return;
    int r = chunk_r[blockIdx.x];
    int base = chunk_off[blockIdx.x];
    int nE = min(TILE_E, offs[r + 1] - base);
    const unsigned short* Wr = W + (size_t)r * (DIM * DIM);

    __shared__ unsigned short wt[128 * 136];   // [k][o] rows padded to 272B
    __shared__ unsigned short xjf[4096];       // A-frag order: ((rt*4+kb)*64+lane)*8+j
    __shared__ float scf[TILE_E];
    __shared__ int sdd[TILE_E];

    int t = threadIdx.x;
    if (t < TILE_E) {
        if (t < nE) {
            int e = eids[base + t];
            int d_ = dst[e];
            sdd[t] = d_;
            scf[t] = ae[e] / denom[d_];
        } else { sdd[t] = 0; scf[t] = 0.f; }
    }
    // stage x_src rows in A-frag order: 32 edges x 16 octets = 512 int4 chunks
#pragma unroll
    for (int p = 0; p < 2; p++) {
        int c = t + 256 * p;
        int e = c >> 4, oct = c & 15;
        int kb = oct >> 2, q = oct & 3, rt = e >> 4, m = e & 15;
        int4 v = make_int4(0, 0, 0, 0);
        if (e < nE)
            v = *(const int4*)(xb + (size_t)src[eids[base + e]] * DIM + oct * 8);
        *(int4*)&xjf[((rt * 4 + kb) * 64 + q * 16 + m) * 8] = v;
    }
    // stage W tile: 128 rows x 16 octets = 2048 int4 chunks
#pragma unroll
    for (int p = 0; p < 8; p++) {
        int c = t + 256 * p;
        int k = c >> 4, oct = c & 15;
        int4 v = *(const int4*)(Wr + k * DIM + oct * 8);
        *(int4*)&wt[k * 136 + oct * 8] = v;
    }
    __syncthreads();

    int w = t >> 6, l = t & 63, n = l & 15, q = l >> 4;
    f32x4 acc[2][2] = {};                       // [ct-local][rt]
#pragma unroll
    for (int kb = 0; kb < 4; kb++) {
        bf16x8 a0 = *(const bf16x8*)&xjf[((0 * 4 + kb) * 64 + l) * 8];
        bf16x8 a1 = *(const bf16x8*)&xjf[((1 * 4 + kb) * 64 + l) * 8];
        int kbase = kb * 32 + q * 8;
#pragma unroll
        for (int c = 0; c < 2; c++) {
            int ob = (w * 2 + c) * 16 + n;
            bf16x8 b;
#pragma unroll
            for (int j = 0; j < 8; j++) b[j] = u2b(wt[(kbase + j) * 136 + ob]);
            acc[c][0] = __builtin_amdgcn_mfma_f32_16x16x32_bf16(a0, b, acc[c][0], 0, 0, 0);
            acc[c][1] = __builtin_amdgcn_mfma_f32_16x16x32_bf16(a1, b, acc[c][1], 0, 0, 0);
        }
    }
#pragma unroll
    for (int c = 0; c < 2; c++) {
        int col = (w * 2 + c) * 16 + n;
#pragma unroll
        for (int rt = 0; rt < 2; rt++) {
#pragma unroll
            for (int rg = 0; rg < 4; rg++) {
                int e = rt * 16 + q * 4 + rg;
                if (e < nE)
                    atomicAdd(&outacc[(size_t)sdd[e] * DIM + col], scf[e] * acc[c][rt][rg]);
            }
        }
    }
}

// ---------- root: out = acc + x @ root + bias via MFMA; mode 1 = relu+bf16, 0 = fp32 ----------
__global__ __launch_bounds__(256) void root_kernel(const unsigned short* __restrict__ xb,
                                                   const float* __restrict__ rootM,
                                                   const float* __restrict__ bias,
                                                   const float* __restrict__ accbuf,
                                                   unsigned short* __restrict__ outb,
                                                   float* __restrict__ outf,
                                                   int mode, int N) {
    int n0 = blockIdx.x * 64;
    __shared__ unsigned short wt[128 * 136];   // root bf16 [k][o] pad
    __shared__ unsigned short xrf[8192];       // 64 rows A-frag order (4 rt)
    int t = threadIdx.x;
    // stage x rows: 64 rows x 16 octets = 1024 int4 chunks
#pragma unroll
    for (int p = 0; p < 4; p++) {
        int c = t + 256 * p;
        int ri = c >> 4, oct = c & 15;
        int kb = oct >> 2, q = oct & 3, rt = ri >> 4, m = ri & 15;
        int4 v = make_int4(0, 0, 0, 0);
        int row = n0 + ri;
        if (row < N) v = *(const int4*)(xb + (size_t)row * DIM + oct * 8);
        *(int4*)&xrf[((rt * 4 + kb) * 64 + q * 16 + m) * 8] = v;
    }
    // stage root fp32 -> bf16: 4096 float4 chunks
#pragma unroll
    for (int p = 0; p < 16; p++) {
        int c = t + 256 * p;
        int k = c >> 5, of = c & 31;
        float4 v = *(const float4*)(rootM + k * DIM + of * 4);
        ushort4 s;
        s.x = f2b(v.x); s.y = f2b(v.y); s.z = f2b(v.z); s.w = f2b(v.w);
        *(ushort4*)&wt[k * 136 + of * 4] = s;
    }
    __syncthreads();

    int w = t >> 6, l = t & 63, n = l & 15, q = l >> 4;
    f32x4 acc[2][4] = {};
#pragma unroll
    for (int kb = 0; kb < 4; kb++) {
        bf16x8 a[4];
#pragma unroll
        for (int rt = 0; rt < 4; rt++) a[rt] = *(const bf16x8*)&xrf[((rt * 4 + kb) * 64 + l) * 8];
        int kbase = kb * 32 + q * 8;
#pragma unroll
        for (int c = 0; c < 2; c++) {
            int ob = (w * 2 + c) * 16 + n;
            bf16x8 b;
#pragma unroll
            for (int j = 0; j < 8; j++) b[j] = u2b(wt[(kbase + j) * 136 + ob]);
#pragma unroll
            for (int rt = 0; rt < 4; rt++)
                acc[c][rt] = __builtin_amdgcn_mfma_f32_16x16x32_bf16(a[rt], b, acc[c][rt], 0, 0, 0);
        }
    }
#pragma unroll
    for (int c = 0; c < 2; c++) {
        int col = (w * 2 + c) * 16 + n;
        float bo = bias[col];
#pragma unroll
        for (int rt = 0; rt < 4; rt++) {
#pragma unroll
            for (int rg = 0; rg < 4; rg++) {
                int row = n0 + rt * 16 + q * 4 + rg;
                if (row < N) {
                    float v = accbuf[(size_t)row * DIM + col] + acc[c][rt][rg] + bo;
                    if (mode) {
                        v = fmaxf(v, 0.f);
                        outb[(size_t)row * DIM + col] = f2b(v);
                    } else {
                        outf[(size_t)row * DIM + col] = v;
                    }
                }
            }
        }
    }
}

extern "C" void kernel_launch(void* const* d_in, const int* in_sizes, int n_in,
                              void* d_out, int out_size, void* d_ws, size_t ws_size,
                              hipStream_t stream) {
    const int N = N_NODES, E = N_EDGES, R = N_REL;

    const int* entity = (const int*)d_in[0];
    const int* eidx   = (const int*)d_in[1];
    const int* src    = eidx;
    const int* dst    = eidx + E;
    const int* etype  = (const int*)d_in[2];
    const float* emb  = (const float*)d_in[3];
    const float* basis1 = (const float*)d_in[4];
    const float* att1   = (const float*)d_in[5];
    const float* w1     = (const float*)d_in[6];
    const float* root1  = (const float*)d_in[7];
    const float* bias1  = (const float*)d_in[8];
    const float* basis2 = (const float*)d_in[9];
    const float* att2   = (const float*)d_in[10];
    const float* w2     = (const float*)d_in[11];
    const float* root2  = (const float*)d_in[12];
    const float* bias2  = (const float*)d_in[13];
    float* out = (float*)d_out;

    size_t off = 0;
    auto alloc = [&](size_t bytes) -> void* {
        void* p = (char*)d_ws + off;
        off += (bytes + 255) & ~(size_t)255;
        return p;
    };
    unsigned short* W  = (unsigned short*)alloc((size_t)R * DIM * DIM * 2);
    unsigned short* xb = (unsigned short*)alloc((size_t)N * DIM * 2);
    unsigned short* hb = (unsigned short*)alloc((size_t)N * DIM * 2);
    float* seg    = (float*)alloc((size_t)N * (2 + DIM) * 4);   // nmax | denom | acc
    unsigned* nmax = (unsigned*)seg;
    float* denom  = seg + N;
    float* acc    = seg + 2 * N;
    float* alpha  = (float*)alloc((size_t)E * 4);
    int* meta     = (int*)alloc((size_t)(R + 1) * 4);   // cnt | nchunks
    int* cnt      = meta;
    int* nchunks  = meta + R;
    int* offs     = (int*)alloc((size_t)(R + 1) * 4);
    int* cursor   = (int*)alloc((size_t)R * 4);
    int* eids     = (int*)alloc((size_t)E * 4);
    int* chunk_r  = (int*)alloc((size_t)MAXCH * 4);
    int* chunk_o  = (int*)alloc((size_t)MAXCH * 4);

    // ---- prep ----
    hipMemsetAsync(meta, 0, (size_t)(R + 1) * 4, stream);
    {
        int total4 = N * DIM / 4;
        gather_kernel<<<(total4 + 255) / 256, 256, 0, stream>>>(
            (const float4*)emb, entity, (ushort4*)xb, total4);
    }
    count_kernel<<<(E + 255) / 256, 256, 0, stream>>>(etype, cnt, E);
    scan_kernel<<<1, 512, 0, stream>>>(cnt, offs, cursor, R, E);
    scatter_kernel<<<(E + 255) / 256, 256, 0, stream>>>(etype, cursor, eids, E);
    chunkbuild_kernel<<<(R + 255) / 256, 256, 0, stream>>>(offs, chunk_r, chunk_o, nchunks, R);

    // ---- layer 1: xb -> hb (relu, bf16) ----
    hipMemsetAsync(seg, 0, (size_t)N * (2 + DIM) * 4, stream);
    logit_kernel<<<E / 4, 256, 0, stream>>>(xb, w1, src, dst, etype, alpha, nmax, E);
    expden_kernel<<<(E + 255) / 256, 256, 0, stream>>>(alpha, dst, nmax, denom, E);
    wmix_kernel<<<dim3(64, 30), 256, 0, stream>>>(att1, basis1, W, R);
    msg_kernel<<<MAXCH, 256, 0, stream>>>(xb, W, chunk_r, chunk_o, nchunks,
                                          eids, offs, src, dst, alpha, denom, acc);
    root_kernel<<<(N + 63) / 64, 256, 0, stream>>>(xb, root1, bias1, acc, hb, nullptr, 1, N);

    // ---- layer 2: hb -> out (fp32) ----
    hipMemsetAsync(seg, 0, (size_t)N * (2 + DIM) * 4, stream);
    logit_kernel<<<E / 4, 256, 0, stream>>>(hb, w2, src, dst, etype, alpha, nmax, E);
    expden_kernel<<<(E + 255) / 256, 256, 0, stream>>>(alpha, dst, nmax, denom, E);
    wmix_kernel<<<dim3(64, 30), 256, 0, stream>>>(att2, basis2, W, R);
    msg_kernel<<<MAXCH, 256, 0, stream>>>(hb, W, chunk_r, chunk_o, nchunks,
                                          eids, offs, src, dst, alpha, denom, acc);
    root_kernel<<<(N + 63) / 64, 256, 0, stream>>>(hb, root2, bias2, acc, nullptr, out, 0, N);
}